// Round 4
// baseline (658.296 us; speedup 1.0000x reference)
//
#include <hip/hip_runtime.h>
#include <hip/hip_bf16.h>
#include <math.h>

#define NN 8192
#define DD 512
#define INV_T 14.285714285714286f   // 1/0.07 ; also the logits_max (diagonal) value

typedef __attribute__((ext_vector_type(8))) short s16x8;  // 8 bf16 = 4 VGPRs
typedef __attribute__((ext_vector_type(4))) float f32x4;
typedef __attribute__((ext_vector_type(4))) int   i32x4;
typedef __attribute__((ext_vector_type(4))) unsigned int u32x4;

__device__ __forceinline__ unsigned short f32_to_bf16(float f) {
  unsigned int u = __float_as_uint(f);
  u += 0x7FFFu + ((u >> 16) & 1u);   // round-to-nearest-even
  return (unsigned short)(u >> 16);
}

// ---------------- Kernel A: normalize rows, emit bf16 ----------------
__global__ __launch_bounds__(256) void normalize_kernel(const float* __restrict__ f,
                                                        unsigned short* __restrict__ fnb) {
  const int wave = threadIdx.x >> 6;
  const int lane = threadIdx.x & 63;
  const int row  = blockIdx.x * 4 + wave;
  const float* src = f + (size_t)row * DD + lane * 8;
  float4 v0 = *(const float4*)src;
  float4 v1 = *(const float4*)(src + 4);
  float ss = v0.x*v0.x + v0.y*v0.y + v0.z*v0.z + v0.w*v0.w
           + v1.x*v1.x + v1.y*v1.y + v1.z*v1.z + v1.w*v1.w;
  #pragma unroll
  for (int o = 32; o; o >>= 1) ss += __shfl_xor(ss, o);
  const float r = 1.0f / fmaxf(sqrtf(ss), 1e-8f);
  ushort4 a, b;
  a.x = f32_to_bf16(v0.x * r); a.y = f32_to_bf16(v0.y * r);
  a.z = f32_to_bf16(v0.z * r); a.w = f32_to_bf16(v0.w * r);
  b.x = f32_to_bf16(v1.x * r); b.y = f32_to_bf16(v1.y * r);
  b.z = f32_to_bf16(v1.z * r); b.w = f32_to_bf16(v1.w * r);
  unsigned short* dst = fnb + (size_t)row * DD + lane * 8;
  *(ushort4*)dst = a;
  *(ushort4*)(dst + 4) = b;
}

// ---------------- Kernel B: barrier-free fused tile ----------------
// 128x128 tile per block, 4 waves each 64x64 (4x4 of 16x16x32 bf16 MFMA).
// Fragments loaded DIRECTLY from global fnb (L2/L3-resident) - no LDS, no
// K-loop barriers. Mask pack (int4 + ballot) runs first per wave; single
// __syncthreads before the epilogue. Bit layout per tile row: 4 x u32,
// word j bit c <-> local col 4c+j.
__global__ __launch_bounds__(256, 3) void fused_kernel(const unsigned short* __restrict__ fnb,
                                                       const int* __restrict__ posm,
                                                       const int* __restrict__ negm,
                                                       float* __restrict__ Spos,
                                                       float* __restrict__ Sneg,
                                                       float* __restrict__ Pcnt) {
  // decode compact triangular block id -> (bi, bj), bi <= bj, 64x64 block grid
  const int bid = blockIdx.x;
  int bi = (int)(64.5 - sqrt(64.5 * 64.5 - 2.0 * (double)bid));
  while (64 * bi - bi * (bi - 1) / 2 > bid) --bi;
  while (64 * (bi + 1) - (bi + 1) * bi / 2 <= bid) ++bi;
  const int bj = bi + (bid - (64 * bi - bi * (bi - 1) / 2));
  const int I = bi * 128;
  const int J = bj * 128;
  const bool offdiag = (bi != bj);

  const int tid  = threadIdx.x;
  const int wave = tid >> 6;
  const int lane = tid & 63;
  const int wm = wave >> 1;            // 0..1 row half
  const int wn = wave & 1;             // 0..1 col half
  const int q   = lane >> 4;           // 0..3
  const int c16 = lane & 15;           // 0..15

  // bit tiles: [msel][local row][word j]; word j bit c <-> col 4c+j
  __shared__ unsigned int bdir[2][128][4];   // rows I.., cols J..
  __shared__ unsigned int btr [2][128][4];   // rows J.., cols I..

  // ---- Phase 1: mask pack; wave -> (tile, msel) ----
  {
    const int tile = wave >> 1;        // 0 = direct, 1 = transposed
    const int msel = wave & 1;         // 0 = pos, 1 = neg
    const int R0 = tile ? J : I;
    const int C0 = tile ? I : J;
    const int* mb = msel ? negm : posm;
    unsigned int (*dst)[4] = tile ? btr[msel] : bdir[msel];
    const int sub  = lane >> 5;        // row within pair
    const int col4 = (lane & 31) * 4;
    if (!(tile && !offdiag)) {         // diag blocks: transposed tile unused
      for (int i = 0; i < 64; i += 4) {       // 4 row-pairs per group (16 KB in flight)
        i32x4 v[4];
        #pragma unroll
        for (int u = 0; u < 4; ++u) {
          const int row = (i + u) * 2 + sub;
          v[u] = __builtin_nontemporal_load(
                   (const i32x4*)(mb + (size_t)(R0 + row) * NN + C0 + col4));
        }
        #pragma unroll
        for (int u = 0; u < 4; ++u) {
          const unsigned long long b0 = __ballot(v[u].x != 0);
          const unsigned long long b1 = __ballot(v[u].y != 0);
          const unsigned long long b2 = __ballot(v[u].z != 0);
          const unsigned long long b3 = __ballot(v[u].w != 0);
          if (lane < 2) {              // lane0 -> row pair*2 (low32), lane1 -> +1 (high32)
            const int sh = lane * 32;
            u32x4 w;
            w.x = (unsigned int)(b0 >> sh);
            w.y = (unsigned int)(b1 >> sh);
            w.z = (unsigned int)(b2 >> sh);
            w.w = (unsigned int)(b3 >> sh);
            *(u32x4*)&dst[(i + u) * 2 + lane][0] = w;
          }
        }
      }
    }
  }

  // ---- Phase 2: GEMM, fragments direct from global (no barriers) ----
  f32x4 acc[4][4];
  const f32x4 z4 = {0.f, 0.f, 0.f, 0.f};
  #pragma unroll
  for (int mt = 0; mt < 4; ++mt)
    #pragma unroll
    for (int nt = 0; nt < 4; ++nt) acc[mt][nt] = z4;

  const unsigned short* aP[4];
  const unsigned short* bP[4];
  #pragma unroll
  for (int t = 0; t < 4; ++t) {
    aP[t] = fnb + (size_t)(I + wm * 64 + t * 16 + c16) * DD + q * 8;
    bP[t] = fnb + (size_t)(J + wn * 64 + t * 16 + c16) * DD + q * 8;
  }
  s16x8 aF[2][4], bF[2][4];
  #pragma unroll
  for (int t = 0; t < 4; ++t) {
    aF[0][t] = *(const s16x8*)aP[t];
    bF[0][t] = *(const s16x8*)bP[t];
  }
  #pragma unroll 2
  for (int kk = 0; kk < DD / 32; ++kk) {
    const int cur = kk & 1, nxt = cur ^ 1;
    if (kk < DD / 32 - 1) {
      const int off = (kk + 1) * 32;
      #pragma unroll
      for (int t = 0; t < 4; ++t) {
        aF[nxt][t] = *(const s16x8*)(aP[t] + off);
        bF[nxt][t] = *(const s16x8*)(bP[t] + off);
      }
    }
    #pragma unroll
    for (int mt = 0; mt < 4; ++mt)
      #pragma unroll
      for (int nt = 0; nt < 4; ++nt)
        acc[mt][nt] = __builtin_amdgcn_mfma_f32_16x16x32_bf16(aF[cur][mt], bF[cur][nt], acc[mt][nt], 0, 0, 0);
  }

  __syncthreads();   // the ONLY barrier: bits ready for epilogue

  // ---- Phase 3: epilogue ----
  const bool hasdiag = (bi == bj) && (wm == wn);

  u32x4 pT4[4], nT4[4];
  if (offdiag) {
    #pragma unroll
    for (int nt = 0; nt < 4; ++nt) {
      const int cl = wn * 64 + nt * 16 + c16;   // local row in transposed tile
      pT4[nt] = *(const u32x4*)&btr[0][cl][0];
      nT4[nt] = *(const u32x4*)&btr[1][cl][0];
    }
  }
  float tsp[4] = {0,0,0,0}, tsn[4] = {0,0,0,0};
  const int jword = c16 & 3;                     // direct-pass word index
  const int cshift = c16 >> 2;                   // + wn*16 + nt*4

  #pragma unroll
  for (int mt = 0; mt < 4; ++mt) {
    const int rl = wm * 64 + mt * 16 + q * 4;    // local row base
    unsigned int pwv[4], nwv[4];
    #pragma unroll
    for (int r = 0; r < 4; ++r) {
      pwv[r] = bdir[0][rl + r][jword];
      nwv[r] = bdir[1][rl + r][jword];
    }
    float dsp[4] = {0,0,0,0}, dsn[4] = {0,0,0,0}, dpc[4] = {0,0,0,0};
    #pragma unroll
    for (int nt = 0; nt < 4; ++nt) {
      float e[4];
      #pragma unroll
      for (int r = 0; r < 4; ++r)
        e[r] = __expf(acc[mt][nt][r] * INV_T - INV_T);
      const int cbit = wn * 16 + nt * 4 + cshift;
      const int cl   = wn * 64 + nt * 16 + c16;  // local col
      #pragma unroll
      for (int r = 0; r < 4; ++r) {
        float pf = (float)((pwv[r] >> cbit) & 1u);
        float nf = (float)((nwv[r] >> cbit) & 1u);
        if (hasdiag && (rl + r == cl)) { pf = 0.f; nf = 0.f; }  // self-contrast diag
        dsp[r] = fmaf(e[r], pf, dsp[r]);
        dsn[r] = fmaf(e[r], nf, dsn[r]);
        dpc[r] += pf;
      }
      if (offdiag) {   // sim(col,row) == sim(row,col); word r, bit tc
        const int tc = wm * 16 + mt * 4 + q;
        const unsigned int* pw = (const unsigned int*)&pT4[nt];
        const unsigned int* nw = (const unsigned int*)&nT4[nt];
        #pragma unroll
        for (int r = 0; r < 4; ++r) {
          tsp[nt] = fmaf(e[r], (float)((pw[r] >> tc) & 1u), tsp[nt]);
          tsn[nt] = fmaf(e[r], (float)((nw[r] >> tc) & 1u), tsn[nt]);
        }
      }
    }
    // reduce over the 16 lanes holding this row's columns
    #pragma unroll
    for (int r = 0; r < 4; ++r) {
      float a = dsp[r], b = dsn[r], p = dpc[r];
      #pragma unroll
      for (int o = 1; o <= 8; o <<= 1) {
        a += __shfl_xor(a, o);
        b += __shfl_xor(b, o);
        p += __shfl_xor(p, o);
      }
      if (c16 == 0) {
        const int row = I + rl + r;
        atomicAdd(&Spos[row], a);
        atomicAdd(&Sneg[row], b);
        atomicAdd(&Pcnt[row], p);
      }
    }
  }

  if (offdiag) {
    #pragma unroll
    for (int nt = 0; nt < 4; ++nt) {
      float a = tsp[nt], b = tsn[nt];
      a += __shfl_xor(a, 16); a += __shfl_xor(a, 32);
      b += __shfl_xor(b, 16); b += __shfl_xor(b, 32);
      const int col = J + wn * 64 + nt * 16 + c16;
      if (q == 0) {
        atomicAdd(&Spos[col], a);
        atomicAdd(&Sneg[col], b);
      }
      if (q == 0 && wm == 0) {   // full-row popcount once (wm waves share rows)
        const unsigned int* pw = (const unsigned int*)&pT4[nt];
        const float pc = (float)(__popc(pw[0]) + __popc(pw[1]) + __popc(pw[2]) + __popc(pw[3]));
        atomicAdd(&Pcnt[col], pc);
      }
    }
  }
}

// ---------------- Kernel C: finalize ----------------
__global__ __launch_bounds__(256) void finalize_kernel(const float* __restrict__ Spos,
                                                       const float* __restrict__ Sneg,
                                                       const float* __restrict__ Pcnt,
                                                       float* __restrict__ out) {
  float local = 0.f;
  for (int i = threadIdx.x; i < NN; i += 256) {
    const float sp = Spos[i], sn = Sneg[i], pc = Pcnt[i];
    const float card = (pc == 0.f) ? 1.f : pc;
    // loss_i = -(sp - log(sn)*pc)/card
    local += (logf(sn) * pc - sp) / card;
  }
  #pragma unroll
  for (int o = 32; o; o >>= 1) local += __shfl_xor(local, o);
  __shared__ float red[4];
  if ((threadIdx.x & 63) == 0) red[threadIdx.x >> 6] = local;
  __syncthreads();
  if (threadIdx.x == 0)
    out[0] = (red[0] + red[1] + red[2] + red[3]) * (1.0f / (float)NN);
}

extern "C" void kernel_launch(void* const* d_in, const int* in_sizes, int n_in,
                              void* d_out, int out_size, void* d_ws, size_t ws_size,
                              hipStream_t stream) {
  const float* feat = (const float*)d_in[0];
  const int* posm   = (const int*)d_in[1];
  const int* negm   = (const int*)d_in[2];
  float* out = (float*)d_out;

  char* ws = (char*)d_ws;
  unsigned short* fnb = (unsigned short*)ws;                 // 8 MB
  float* Spos = (float*)(ws + (size_t)8 * 1024 * 1024);
  float* Sneg = Spos + NN;
  float* Pcnt = Sneg + NN;

  hipMemsetAsync(Spos, 0, 3 * NN * sizeof(float), stream);
  normalize_kernel<<<NN / 4, 256, 0, stream>>>(feat, fnb);
  fused_kernel<<<2080, 256, 0, stream>>>(fnb, posm, negm, Spos, Sneg, Pcnt);
  finalize_kernel<<<1, 256, 0, stream>>>(Spos, Sneg, Pcnt, out);
}

// Round 5
// 642.067 us; speedup vs baseline: 1.0253x; 1.0253x over previous
//
#include <hip/hip_runtime.h>
#include <hip/hip_bf16.h>
#include <math.h>

#define NN 8192
#define DD 512
#define INV_T 14.285714285714286f   // 1/0.07 ; also the logits_max (diagonal) value

typedef __attribute__((ext_vector_type(8))) short s16x8;  // 8 bf16 = 4 VGPRs
typedef __attribute__((ext_vector_type(4))) float f32x4;
typedef __attribute__((ext_vector_type(4))) int   i32x4;
typedef __attribute__((ext_vector_type(4))) unsigned int u32x4;

__device__ __forceinline__ unsigned short f32_to_bf16(float f) {
  unsigned int u = __float_as_uint(f);
  u += 0x7FFFu + ((u >> 16) & 1u);   // round-to-nearest-even
  return (unsigned short)(u >> 16);
}

// ---------------- Kernel A: normalize rows, emit bf16 ----------------
__global__ __launch_bounds__(256) void normalize_kernel(const float* __restrict__ f,
                                                        unsigned short* __restrict__ fnb) {
  const int wave = threadIdx.x >> 6;
  const int lane = threadIdx.x & 63;
  const int row  = blockIdx.x * 4 + wave;
  const float* src = f + (size_t)row * DD + lane * 8;
  float4 v0 = *(const float4*)src;
  float4 v1 = *(const float4*)(src + 4);
  float ss = v0.x*v0.x + v0.y*v0.y + v0.z*v0.z + v0.w*v0.w
           + v1.x*v1.x + v1.y*v1.y + v1.z*v1.z + v1.w*v1.w;
  #pragma unroll
  for (int o = 32; o; o >>= 1) ss += __shfl_xor(ss, o);
  const float r = 1.0f / fmaxf(sqrtf(ss), 1e-8f);
  ushort4 a, b;
  a.x = f32_to_bf16(v0.x * r); a.y = f32_to_bf16(v0.y * r);
  a.z = f32_to_bf16(v0.z * r); a.w = f32_to_bf16(v0.w * r);
  b.x = f32_to_bf16(v1.x * r); b.y = f32_to_bf16(v1.y * r);
  b.z = f32_to_bf16(v1.z * r); b.w = f32_to_bf16(v1.w * r);
  unsigned short* dst = fnb + (size_t)row * DD + lane * 8;
  *(ushort4*)dst = a;
  *(ushort4*)(dst + 4) = b;
}

// ---------------- Kernel B: fused tile, mask loads pipelined through K-loop ----------------
// 128x128 tile per block, 4 waves each 64x64 (4x4 of 16x16x32 bf16 MFMA).
// GEMM fragments direct from global fnb (L2/L3-resident), no K-loop barriers.
// Mask ingestion: 16 groups of 4 int4 loads per wave, issued 3 K-iterations
// ahead of their ballot-drain -> each wave keeps ~16KB of HBM loads in flight
// under the MFMA stream. Single __syncthreads before the epilogue.
__global__ __launch_bounds__(256, 2) void fused_kernel(const unsigned short* __restrict__ fnb,
                                                       const int* __restrict__ posm,
                                                       const int* __restrict__ negm,
                                                       float* __restrict__ Spos,
                                                       float* __restrict__ Sneg,
                                                       float* __restrict__ Pcnt) {
  // decode compact triangular block id -> (bi, bj), bi <= bj, 64x64 block grid
  const int bid = blockIdx.x;
  int bi = (int)(64.5 - sqrt(64.5 * 64.5 - 2.0 * (double)bid));
  while (64 * bi - bi * (bi - 1) / 2 > bid) --bi;
  while (64 * (bi + 1) - (bi + 1) * bi / 2 <= bid) ++bi;
  const int bj = bi + (bid - (64 * bi - bi * (bi - 1) / 2));
  const int I = bi * 128;
  const int J = bj * 128;
  const bool offdiag = (bi != bj);

  const int tid  = threadIdx.x;
  const int wave = tid >> 6;
  const int lane = tid & 63;
  const int wm = wave >> 1;            // 0..1 row half
  const int wn = wave & 1;             // 0..1 col half
  const int q   = lane >> 4;           // 0..3
  const int c16 = lane & 15;           // 0..15

  // bit tiles: [msel][local row][word j]; word j bit c <-> col 4c+j
  __shared__ unsigned int bdir[2][128][4];   // rows I.., cols J..
  __shared__ unsigned int btr [2][128][4];   // rows J.., cols I..

  // ---- mask pipeline setup: wave -> (tile, msel) ----
  const int tile = wave >> 1;          // 0 = direct, 1 = transposed
  const int msel = wave & 1;           // 0 = pos, 1 = neg
  const int R0 = tile ? J : I;
  const int C0 = tile ? I : J;
  const int* mb = msel ? negm : posm;
  unsigned int (*mdst)[4] = tile ? btr[msel] : bdir[msel];
  const bool do_mask = !(tile && !offdiag);   // diag blocks: transposed tile unused
  const int sub  = lane >> 5;          // row within pair
  const int col4 = (lane & 31) * 4;
  const int* mrow = mb + (size_t)R0 * NN + C0 + col4;

  // group g (0..15) covers tile rows 8g..8g+7; load u covers rows 8g+2u+sub
  i32x4 mg[4][4];                      // [slot g&3][u] -- register pipeline buffer

  #define MISSUE(g)                                                           \
    if (do_mask && (g) < 16) {                                                \
      _Pragma("unroll")                                                       \
      for (int u = 0; u < 4; ++u)                                             \
        mg[(g) & 3][u] = __builtin_nontemporal_load(                          \
            (const i32x4*)(mrow + (size_t)(8 * (g) + 2 * u + sub) * NN));     \
    }

  #define MDRAIN(g)                                                           \
    if (do_mask) {                                                            \
      _Pragma("unroll")                                                       \
      for (int u = 0; u < 4; ++u) {                                           \
        const i32x4 v = mg[(g) & 3][u];                                       \
        const unsigned long long b0 = __ballot(v.x != 0);                     \
        const unsigned long long b1 = __ballot(v.y != 0);                     \
        const unsigned long long b2 = __ballot(v.z != 0);                     \
        const unsigned long long b3 = __ballot(v.w != 0);                     \
        if (lane < 2) {                                                       \
          const int sh = lane * 32;                                           \
          u32x4 w;                                                            \
          w.x = (unsigned int)(b0 >> sh);                                     \
          w.y = (unsigned int)(b1 >> sh);                                     \
          w.z = (unsigned int)(b2 >> sh);                                     \
          w.w = (unsigned int)(b3 >> sh);                                     \
          *(u32x4*)&mdst[8 * (g) + 2 * u + lane][0] = w;                      \
        }                                                                     \
      }                                                                       \
    }

  // ---- GEMM + pipelined mask stream ----
  f32x4 acc[4][4];
  const f32x4 z4 = {0.f, 0.f, 0.f, 0.f};
  #pragma unroll
  for (int mt = 0; mt < 4; ++mt)
    #pragma unroll
    for (int nt = 0; nt < 4; ++nt) acc[mt][nt] = z4;

  const unsigned short* aP[4];
  const unsigned short* bP[4];
  #pragma unroll
  for (int t = 0; t < 4; ++t) {
    aP[t] = fnb + (size_t)(I + wm * 64 + t * 16 + c16) * DD + q * 8;
    bP[t] = fnb + (size_t)(J + wn * 64 + t * 16 + c16) * DD + q * 8;
  }

  MISSUE(0) MISSUE(1) MISSUE(2)

  #pragma unroll
  for (int kk = 0; kk < 16; ++kk) {
    MISSUE(kk + 3)                      // issue 3 iterations ahead of drain
    s16x8 aF[4], bF[4];
    const int off = kk * 32;
    #pragma unroll
    for (int t = 0; t < 4; ++t) {
      aF[t] = *(const s16x8*)(aP[t] + off);
      bF[t] = *(const s16x8*)(bP[t] + off);
    }
    MDRAIN(kk)                          // ballot data issued ~3 iterations ago
    #pragma unroll
    for (int mt = 0; mt < 4; ++mt)
      #pragma unroll
      for (int nt = 0; nt < 4; ++nt)
        acc[mt][nt] = __builtin_amdgcn_mfma_f32_16x16x32_bf16(aF[mt], bF[nt], acc[mt][nt], 0, 0, 0);
  }

  __syncthreads();   // the ONLY barrier: bit tiles ready for epilogue

  // ---- epilogue ----
  const bool hasdiag = (bi == bj) && (wm == wn);

  u32x4 pT4[4], nT4[4];
  if (offdiag) {
    #pragma unroll
    for (int nt = 0; nt < 4; ++nt) {
      const int cl = wn * 64 + nt * 16 + c16;   // local row in transposed tile
      pT4[nt] = *(const u32x4*)&btr[0][cl][0];
      nT4[nt] = *(const u32x4*)&btr[1][cl][0];
    }
  }
  float tsp[4] = {0,0,0,0}, tsn[4] = {0,0,0,0};
  const int jword = c16 & 3;                     // direct-pass word index
  const int cshift = c16 >> 2;                   // + wn*16 + nt*4

  #pragma unroll
  for (int mt = 0; mt < 4; ++mt) {
    const int rl = wm * 64 + mt * 16 + q * 4;    // local row base
    unsigned int pwv[4], nwv[4];
    #pragma unroll
    for (int r = 0; r < 4; ++r) {
      pwv[r] = bdir[0][rl + r][jword];
      nwv[r] = bdir[1][rl + r][jword];
    }
    float dsp[4] = {0,0,0,0}, dsn[4] = {0,0,0,0}, dpc[4] = {0,0,0,0};
    #pragma unroll
    for (int nt = 0; nt < 4; ++nt) {
      float e[4];
      #pragma unroll
      for (int r = 0; r < 4; ++r)
        e[r] = __expf(acc[mt][nt][r] * INV_T - INV_T);
      const int cbit = wn * 16 + nt * 4 + cshift;
      const int cl   = wn * 64 + nt * 16 + c16;  // local col
      #pragma unroll
      for (int r = 0; r < 4; ++r) {
        float pf = (float)((pwv[r] >> cbit) & 1u);
        float nf = (float)((nwv[r] >> cbit) & 1u);
        if (hasdiag && (rl + r == cl)) { pf = 0.f; nf = 0.f; }  // self-contrast diag
        dsp[r] = fmaf(e[r], pf, dsp[r]);
        dsn[r] = fmaf(e[r], nf, dsn[r]);
        dpc[r] += pf;
      }
      if (offdiag) {   // sim(col,row) == sim(row,col); word r, bit tc
        const int tc = wm * 16 + mt * 4 + q;
        const unsigned int* pw = (const unsigned int*)&pT4[nt];
        const unsigned int* nw = (const unsigned int*)&nT4[nt];
        #pragma unroll
        for (int r = 0; r < 4; ++r) {
          tsp[nt] = fmaf(e[r], (float)((pw[r] >> tc) & 1u), tsp[nt]);
          tsn[nt] = fmaf(e[r], (float)((nw[r] >> tc) & 1u), tsn[nt]);
        }
      }
    }
    // reduce over the 16 lanes holding this row's columns
    #pragma unroll
    for (int r = 0; r < 4; ++r) {
      float a = dsp[r], b = dsn[r], p = dpc[r];
      #pragma unroll
      for (int o = 1; o <= 8; o <<= 1) {
        a += __shfl_xor(a, o);
        b += __shfl_xor(b, o);
        p += __shfl_xor(p, o);
      }
      if (c16 == 0) {
        const int row = I + rl + r;
        atomicAdd(&Spos[row], a);
        atomicAdd(&Sneg[row], b);
        atomicAdd(&Pcnt[row], p);
      }
    }
  }

  if (offdiag) {
    #pragma unroll
    for (int nt = 0; nt < 4; ++nt) {
      float a = tsp[nt], b = tsn[nt];
      a += __shfl_xor(a, 16); a += __shfl_xor(a, 32);
      b += __shfl_xor(b, 16); b += __shfl_xor(b, 32);
      const int col = J + wn * 64 + nt * 16 + c16;
      if (q == 0) {
        atomicAdd(&Spos[col], a);
        atomicAdd(&Sneg[col], b);
      }
      if (q == 0 && wm == 0) {   // full-row popcount once (wm waves share rows)
        const unsigned int* pw = (const unsigned int*)&pT4[nt];
        const float pc = (float)(__popc(pw[0]) + __popc(pw[1]) + __popc(pw[2]) + __popc(pw[3]));
        atomicAdd(&Pcnt[col], pc);
      }
    }
  }
}

// ---------------- Kernel C: finalize ----------------
__global__ __launch_bounds__(256) void finalize_kernel(const float* __restrict__ Spos,
                                                       const float* __restrict__ Sneg,
                                                       const float* __restrict__ Pcnt,
                                                       float* __restrict__ out) {
  float local = 0.f;
  for (int i = threadIdx.x; i < NN; i += 256) {
    const float sp = Spos[i], sn = Sneg[i], pc = Pcnt[i];
    const float card = (pc == 0.f) ? 1.f : pc;
    // loss_i = -(sp - log(sn)*pc)/card
    local += (logf(sn) * pc - sp) / card;
  }
  #pragma unroll
  for (int o = 32; o; o >>= 1) local += __shfl_xor(local, o);
  __shared__ float red[4];
  if ((threadIdx.x & 63) == 0) red[threadIdx.x >> 6] = local;
  __syncthreads();
  if (threadIdx.x == 0)
    out[0] = (red[0] + red[1] + red[2] + red[3]) * (1.0f / (float)NN);
}

extern "C" void kernel_launch(void* const* d_in, const int* in_sizes, int n_in,
                              void* d_out, int out_size, void* d_ws, size_t ws_size,
                              hipStream_t stream) {
  const float* feat = (const float*)d_in[0];
  const int* posm   = (const int*)d_in[1];
  const int* negm   = (const int*)d_in[2];
  float* out = (float*)d_out;

  char* ws = (char*)d_ws;
  unsigned short* fnb = (unsigned short*)ws;                 // 8 MB
  float* Spos = (float*)(ws + (size_t)8 * 1024 * 1024);
  float* Sneg = Spos + NN;
  float* Pcnt = Sneg + NN;

  hipMemsetAsync(Spos, 0, 3 * NN * sizeof(float), stream);
  normalize_kernel<<<NN / 4, 256, 0, stream>>>(feat, fnb);
  fused_kernel<<<2080, 256, 0, stream>>>(fnb, posm, negm, Spos, Sneg, Pcnt);
  finalize_kernel<<<1, 256, 0, stream>>>(Spos, Sneg, Pcnt, out);
}